// Round 11
// baseline (322.107 us; speedup 1.0000x reference)
//
#include <hip/hip_runtime.h>

// AdaMoeLayer: B=8,S=4096,D=512,E=8 -> T=32768 tokens
// Round 13: TLP attack. All plateau rounds (161-166us) ran 8 waves/CU; this
// round runs 16 (4 blocks/CU x 4 waves) with a deliberately SIMPLE schedule
// (R5 rhythm: stage s+1 -> compute s -> one __syncthreads), trusting m114
// inter-block overlap to hide the drain instead of intra-block pipelining.
//  - Single-GEMM numerics (R10-verified): A[t,e*512+d] = w[t,e]*Xbf[t,d],
//    scaled at stage time (reg->scale->swizzled ds_write); no tmp/fold.
//  - 128x128 tile, BK=32, 128 steps. LDS: A 2x8KB + B 2x8KB + sWbT 4KB = 36KB
//    -> 4 blocks/CU. grid 1024 = fully resident. __launch_bounds__(256,4).
//  - B via global_load_lds, pre-swizzled source (R12's BK=32 swizzle, 0-conflict
//    verified): LDS slot (row, phys p) holds chunk c = p ^ ((row>>1)&3).
//  - Per thread per step: 2 A-reg loads + 2 B gld_lds + 16 scale-VALU + 2
//    ds_write_b128; per wave: 8 ds_read_b128 + 16 MFMA.
//  Kernel 1: R11 wave-per-token gating + cvt + Bt transpose (verbatim).

#define T_TOKENS 32768
#define DDIM 512
#define KDIM 4096
#define SLOTK 4096   // ushorts per 128x32 buffer (8 KB)

typedef __attribute__((ext_vector_type(8))) short short8;
typedef __attribute__((ext_vector_type(4))) float floatx4;
typedef __bf16 bf16x2 __attribute__((ext_vector_type(2)));

__device__ __forceinline__ unsigned short f2bf(float f) {
    unsigned int u = __float_as_uint(f);
    u += 0x7FFFu + ((u >> 16) & 1u);   // RNE
    return (unsigned short)(u >> 16);
}

__device__ __forceinline__ unsigned int pk2(float a, float b) {
#if __has_builtin(__builtin_amdgcn_cvt_pk_bf16_f32)
    bf16x2 v = __builtin_amdgcn_cvt_pk_bf16_f32(a, b);
    return __builtin_bit_cast(unsigned int, v);
#else
    return (unsigned int)f2bf(a) | ((unsigned int)f2bf(b) << 16);
#endif
}

__device__ __forceinline__ void async_copy16(const void* g, void* l) {
    __builtin_amdgcn_global_load_lds(
        (const __attribute__((address_space(1))) void*)g,
        (__attribute__((address_space(3))) void*)l, 16, 0, 0);
}

// scale one packed bf16-pair by w (f32 math), repack
__device__ __forceinline__ unsigned int scale_pair(unsigned int u, float w) {
    float lo = __uint_as_float(u << 16) * w;
    float hi = __uint_as_float(u & 0xFFFF0000u) * w;
    return pk2(lo, hi);
}

// ------- Kernel 1 (fused): gating -> wbuf[T,8] + x->Xbf  |  build Bt -------
// (verbatim from R11 — verified)
__global__ __launch_bounds__(256) void gating_cvt_bt(
    const float* __restrict__ x, const float* __restrict__ Wg,
    const float* __restrict__ bg, const float* __restrict__ Wt,
    const float* __restrict__ bt, float* __restrict__ wbuf,
    unsigned short* __restrict__ Xbf,
    const float* __restrict__ Wexp, unsigned short* __restrict__ Bt)
{
    const int tid = threadIdx.x;

    if (blockIdx.x >= 512) {
        __shared__ float tile[64][65];
        const int bb = blockIdx.x - 512;
        const int k0 = (bb & 63) * 64;
        const int n0 = (bb >> 6) * 64;
        const int r = tid >> 4, cq = tid & 15;
#pragma unroll
        for (int p = 0; p < 4; ++p) {
            const int rr = p * 16 + r;
            const float4 v = *(const float4*)(Wexp + (size_t)(k0 + rr) * 512 + n0 + cq * 4);
            tile[rr][cq * 4 + 0] = v.x;
            tile[rr][cq * 4 + 1] = v.y;
            tile[rr][cq * 4 + 2] = v.z;
            tile[rr][cq * 4 + 3] = v.w;
        }
        __syncthreads();
        const int rn = tid >> 2;
        const int kq = tid & 3;
        alignas(16) unsigned short buf[16];
#pragma unroll
        for (int j = 0; j < 16; ++j) buf[j] = f2bf(tile[kq * 16 + j][rn]);
        unsigned short* dst = Bt + (size_t)(n0 + rn) * KDIM + k0 + kq * 16;
        *(uint4*)(dst) = *(const uint4*)(buf);
        *(uint4*)(dst + 8) = *(const uint4*)(buf + 8);
        return;
    }

    const int wv = tid >> 6;
    const int lane = tid & 63;

    float4 wg[16];
    {
        const float4* wgp = (const float4*)(Wg + lane * 64);
#pragma unroll
        for (int c = 0; c < 16; ++c) wg[c] = wgp[c];
    }
    const float4 wt0 = *(const float4*)(Wt + lane * 8);
    const float4 wt1 = *(const float4*)(Wt + lane * 8 + 4);
    const float bgv[8] = {bg[0], bg[1], bg[2], bg[3], bg[4], bg[5], bg[6], bg[7]};
    const float btv = bt[0];

    for (int it = 0; it < 16; ++it) {
        const int t = blockIdx.x * 64 + wv * 16 + it;
        const float* xp = x + (size_t)t * 512 + lane * 8;
        const float4 a0 = *(const float4*)(xp);
        const float4 a1 = *(const float4*)(xp + 4);

        uint2 pk0, pk1;
        pk0.x = pk2(a0.x, a0.y);
        pk0.y = pk2(a0.z, a0.w);
        pk1.x = pk2(a1.x, a1.y);
        pk1.y = pk2(a1.z, a1.w);
        uint2* xd = (uint2*)(Xbf + (size_t)t * 512 + lane * 8);
        xd[0] = pk0;
        xd[1] = pk1;

        const float xv[8] = {a0.x, a0.y, a0.z, a0.w, a1.x, a1.y, a1.z, a1.w};
        const float wtv[8] = {wt0.x, wt0.y, wt0.z, wt0.w, wt1.x, wt1.y, wt1.z, wt1.w};
        float g[9];
#pragma unroll
        for (int e = 0; e < 9; ++e) g[e] = 0.f;
#pragma unroll
        for (int j = 0; j < 8; ++j) {
            const float4 wlo = wg[j * 2];
            const float4 whi = wg[j * 2 + 1];
            g[0] = fmaf(xv[j], wlo.x, g[0]);
            g[1] = fmaf(xv[j], wlo.y, g[1]);
            g[2] = fmaf(xv[j], wlo.z, g[2]);
            g[3] = fmaf(xv[j], wlo.w, g[3]);
            g[4] = fmaf(xv[j], whi.x, g[4]);
            g[5] = fmaf(xv[j], whi.y, g[5]);
            g[6] = fmaf(xv[j], whi.z, g[6]);
            g[7] = fmaf(xv[j], whi.w, g[7]);
            g[8] = fmaf(xv[j], wtv[j], g[8]);
        }
#pragma unroll
        for (int e = 0; e < 9; ++e) {
            g[e] += __shfl_xor(g[e], 1);
            g[e] += __shfl_xor(g[e], 2);
            g[e] += __shfl_xor(g[e], 4);
            g[e] += __shfl_xor(g[e], 8);
            g[e] += __shfl_xor(g[e], 16);
            g[e] += __shfl_xor(g[e], 32);
        }
        if (lane == 0) {
#pragma unroll
            for (int e = 0; e < 8; ++e) g[e] += bgv[e];
            g[8] += btv;
            float m = g[0];
#pragma unroll
            for (int e = 1; e < 8; ++e) m = fmaxf(m, g[e]);
            float s = 0.f;
            float p[8];
#pragma unroll
            for (int e = 0; e < 8; ++e) { p[e] = __expf(g[e] - m); s += p[e]; }
            const float inv = 1.f / s;
            const float thr = 0.25f / (1.f + __expf(-g[8]));
            float w8[8];
            float ws = 0.f;
#pragma unroll
            for (int e = 0; e < 8; ++e) {
                float a = p[e] * inv - thr;
                w8[e] = a > 0.f ? a : 0.f;
                ws += w8[e];
            }
            if (ws == 0.f) ws = 1.f;
            const float invw = 1.f / ws;
            float4 o0, o1;
            o0.x = w8[0] * invw; o0.y = w8[1] * invw; o0.z = w8[2] * invw; o0.w = w8[3] * invw;
            o1.x = w8[4] * invw; o1.y = w8[5] * invw; o1.z = w8[6] * invw; o1.w = w8[7] * invw;
            float4* op = (float4*)(wbuf + (size_t)t * 8);
            op[0] = o0;
            op[1] = o1;
        }
    }
}

// ------------- Kernel 2: 128x128 GEMM, BK=32, 4 blocks/CU ------------------
// LDS slot (row, phys p) holds chunk c = p ^ ((row>>1)&3); addr = row*32+p*8.
__global__ __launch_bounds__(256, 4) void moe_gemm(
    const unsigned short* __restrict__ Xbf, const float* __restrict__ wbuf,
    const float* __restrict__ bexp, const unsigned short* __restrict__ Bt,
    float* __restrict__ out)
{
    __shared__ alignas(16) unsigned short Asl[2 * SLOTK];  // 16 KB
    __shared__ alignas(16) unsigned short Bsl[2 * SLOTK];  // 16 KB
    __shared__ float sWbT[8 * 128];                        // 4 KB [e][row]

    const int tid = threadIdx.x;
    const int wave = tid >> 6;     // 0..3
    const int lane = tid & 63;
    const int wm = wave >> 1;      // 0..1: 64-row half
    const int wn = wave & 1;       // 0..1: 64-col half
    const int lm = lane & 15;
    const int lq = lane >> 4;
    // A stage map: rows arow, arow+64; logical chunk apc; phys acg
    const int arow = tid >> 2;     // 0..63
    const int apc = tid & 3;
    const int acg = apc ^ ((tid >> 3) & 3);       // == apc ^ ((arow>>1)&3)
    // B gld_lds source chunk (dst linear): lane covers row w*16+(l>>2), phys l&3
    const int bcg = (lane & 3) ^ ((lane >> 3) & 3);
    // read phys chunk for rows wX*64 + f*16 + lm
    const int prd = lq ^ ((lm >> 1) & 3);

    // XCD pairing: lin%8 = XCD; 4 n-blocks of a t-tile consecutive (R5-proven)
    const int lin = blockIdx.x;
    const int g = lin & 7;
    const int j_ = lin >> 3;                  // 0..127
    const int t0 = (g * 32 + (j_ >> 2)) * 128;
    const int n0 = (j_ & 3) * 128;

    // sWbT[e][row] = wbuf[t0+row][e]
    {
        const int row = tid >> 1, half = tid & 1;
        const float4 w4 = *(const float4*)(wbuf + (size_t)(t0 + row) * 8 + half * 4);
        sWbT[(half * 4 + 0) * 128 + row] = w4.x;
        sWbT[(half * 4 + 1) * 128 + row] = w4.y;
        sWbT[(half * 4 + 2) * 128 + row] = w4.z;
        sWbT[(half * 4 + 3) * 128 + row] = w4.w;
    }

#define LOADA(s_)                                                               \
    {                                                                           \
        const int d0_ = ((s_) & 15) << 5;                                       \
        ar[0] = *(const uint4*)(Xbf + (size_t)(t0 + arow) * 512 + d0_ + apc * 8); \
        ar[1] = *(const uint4*)(Xbf + (size_t)(t0 + 64 + arow) * 512 + d0_ + apc * 8); \
    }
#define AWRITE(s_, buf_)                                                        \
    {                                                                           \
        const int e1 = (s_) >> 4;                                               \
        _Pragma("unroll")                                                       \
        for (int i = 0; i < 2; ++i) {                                           \
            const float w = sWbT[e1 * 128 + i * 64 + arow];                     \
            uint4 o;                                                            \
            o.x = scale_pair(ar[i].x, w);                                       \
            o.y = scale_pair(ar[i].y, w);                                       \
            o.z = scale_pair(ar[i].z, w);                                       \
            o.w = scale_pair(ar[i].w, w);                                       \
            *(uint4*)(Asl + (buf_) * SLOTK + (i * 64 + arow) * 32 + acg * 8) = o; \
        }                                                                       \
    }
#define STAGE_B(s_, buf_)                                                       \
    {                                                                           \
        _Pragma("unroll")                                                       \
        for (int i = 0; i < 2; ++i)                                             \
            async_copy16(Bt + (size_t)(n0 + i * 64 + wave * 16 + (lane >> 2)) * KDIM \
                             + (s_) * 32 + bcg * 8,                             \
                         Bsl + (buf_) * SLOTK + (i * 64 + wave * 16) * 32);     \
    }

    floatx4 acc[4][4];
#pragma unroll
    for (int i = 0; i < 4; ++i)
#pragma unroll
        for (int j = 0; j < 4; ++j) acc[i][j] = (floatx4){0.f, 0.f, 0.f, 0.f};

    uint4 ar[2];

    // ---- prologue ----
    LOADA(0);
    STAGE_B(0, 0);
    __syncthreads();      // sWbT visible, B(0) landed, ar(0) loaded (vmcnt 0)
    AWRITE(0, 0);
    __syncthreads();      // A(0) visible

    for (int s = 0; s < 128; ++s) {
        const int buf = s & 1;
        if (s < 127) {
            LOADA(s + 1);
            STAGE_B(s + 1, buf ^ 1);
        }
        // ---- compute step s ----
        {
            const unsigned short* Ab = Asl + buf * SLOTK;
            const unsigned short* Bb = Bsl + buf * SLOTK;
            short8 af[4], b[4];
#pragma unroll
            for (int ii = 0; ii < 4; ++ii) {
                const int row = wm * 64 + ii * 16 + lm;
                af[ii] = *(const short8*)(Ab + row * 32 + prd * 8);
            }
#pragma unroll
            for (int j = 0; j < 4; ++j) {
                const int row = wn * 64 + j * 16 + lm;
                b[j] = *(const short8*)(Bb + row * 32 + prd * 8);
            }
            __builtin_amdgcn_s_setprio(1);
#pragma unroll
            for (int ii = 0; ii < 4; ++ii)
#pragma unroll
                for (int j = 0; j < 4; ++j)
                    acc[ii][j] = __builtin_amdgcn_mfma_f32_16x16x32_bf16(
                        af[ii], b[j], acc[ii][j], 0, 0, 0);
            __builtin_amdgcn_s_setprio(0);
        }
        // ---- finish staging s+1 (scale+write A into buf^1) ----
        if (s < 127) AWRITE(s + 1, buf ^ 1);
        __syncthreads();  // drains B gld_lds (vmcnt) + A ds_writes (lgkm)
    }

    // ---- epilogue: out = acc + sum_e w[t,e]*b_exp[e,col] (R10-verified) ----
    float bc[4][8];
#pragma unroll
    for (int j = 0; j < 4; ++j) {
        const int col = n0 + wn * 64 + j * 16 + lm;
#pragma unroll
        for (int e = 0; e < 8; ++e) bc[j][e] = bexp[e * 512 + col];
    }
#pragma unroll
    for (int i = 0; i < 4; ++i)
#pragma unroll
        for (int r = 0; r < 4; ++r) {
            const int rowl = wm * 64 + i * 16 + lq * 4 + r;
            const float4 w0 = *(const float4*)(wbuf + (size_t)(t0 + rowl) * 8);
            const float4 w1 = *(const float4*)(wbuf + (size_t)(t0 + rowl) * 8 + 4);
            float* op = out + (size_t)(t0 + rowl) * 512 + n0 + wn * 64 + lm;
#pragma unroll
            for (int j = 0; j < 4; ++j) {
                float bias = w0.x * bc[j][0];
                bias = fmaf(w0.y, bc[j][1], bias);
                bias = fmaf(w0.z, bc[j][2], bias);
                bias = fmaf(w0.w, bc[j][3], bias);
                bias = fmaf(w1.x, bc[j][4], bias);
                bias = fmaf(w1.y, bc[j][5], bias);
                bias = fmaf(w1.z, bc[j][6], bias);
                bias = fmaf(w1.w, bc[j][7], bias);
                op[j * 16] = acc[i][j][r] + bias;
            }
        }
#undef LOADA
#undef AWRITE
#undef STAGE_B
}

extern "C" void kernel_launch(void* const* d_in, const int* in_sizes, int n_in,
                              void* d_out, int out_size, void* d_ws, size_t ws_size,
                              hipStream_t stream) {
    const float* x   = (const float*)d_in[0];
    const float* Wg  = (const float*)d_in[1];
    const float* bg  = (const float*)d_in[2];
    const float* Wt  = (const float*)d_in[3];
    const float* bt  = (const float*)d_in[4];
    const float* Wex = (const float*)d_in[5];
    const float* bex = (const float*)d_in[6];
    float* out = (float*)d_out;

    // ws layout: Xbf bf16 [32768][512] = 32 MB; Bt bf16 [512][4096] = 4 MB;
    //            wbuf fp32 [32768][8] = 1 MB.  Total 37 MB.
    unsigned short* Xbf = (unsigned short*)d_ws;
    unsigned short* Bt  = (unsigned short*)((char*)d_ws + (size_t)T_TOKENS * DDIM * 2);
    float* wbuf = (float*)((char*)d_ws + (size_t)T_TOKENS * DDIM * 2
                                       + (size_t)DDIM * KDIM * 2);

    gating_cvt_bt<<<1024, 256, 0, stream>>>(x, Wg, bg, Wt, bt, wbuf, Xbf, Wex, Bt);
    moe_gemm<<<1024, 256, 0, stream>>>(Xbf, wbuf, bex, Bt, out);
}

// Round 12
// 302.308 us; speedup vs baseline: 1.0655x; 1.0655x over previous
//
#include <hip/hip_runtime.h>

// AdaMoeLayer: B=8,S=4096,D=512,E=8 -> T=32768 tokens
// Round 14: EXPERT SPARSITY. weights=relu(softmax-thr) zeroes most experts
// (~3-4/8 active). Skipping w==0 experts is bit-exact (fmaf(0,t,a)==a).
// Tokens are counting-sorted by 8-bit expert mask so 128-token tiles are
// mask-homogeneous; the R5 fold-GEMM (166us, verified) then loops only over
// the tile's OR-mask experts. Worst case degenerates to dense R5.
//  1. gating_cvt_bt: R11 wave-per-token gating + cvt + Bt transpose, plus
//     tmask[t] (bit e <=> w8[e]>0) and global hist[mask] accumulation.
//  2. scan_offsets: exclusive prefix over hist[256].
//  3. scatter_perm: pos = offset[mask]+rank; perm[pos]=t; tilemask |= mask.
//  4. moe_gemm: R5 structure (128x128, BK=64, dbuf, 2 blk/CU, fold), rows
//     indirected via sPerm; expert loop = set bits of tilemask[tt]; output
//     rows scattered to out[perm[...]]. Expert fold order stays ascending.

#define T_TOKENS 32768
#define DDIM 512
#define KDIM 4096

typedef __attribute__((ext_vector_type(8))) short short8;
typedef __attribute__((ext_vector_type(4))) float floatx4;
typedef __bf16 bf16x2 __attribute__((ext_vector_type(2)));

__device__ __forceinline__ unsigned short f2bf(float f) {
    unsigned int u = __float_as_uint(f);
    u += 0x7FFFu + ((u >> 16) & 1u);   // RNE
    return (unsigned short)(u >> 16);
}

__device__ __forceinline__ unsigned int pk2(float a, float b) {
#if __has_builtin(__builtin_amdgcn_cvt_pk_bf16_f32)
    bf16x2 v = __builtin_amdgcn_cvt_pk_bf16_f32(a, b);
    return __builtin_bit_cast(unsigned int, v);
#else
    return (unsigned int)f2bf(a) | ((unsigned int)f2bf(b) << 16);
#endif
}

__device__ __forceinline__ void async_copy16(const void* g, void* l) {
    __builtin_amdgcn_global_load_lds(
        (const __attribute__((address_space(1))) void*)g,
        (__attribute__((address_space(3))) void*)l, 16, 0, 0);
}

// ------------------ Kernel 0: zero control arrays (capture-safe) -----------
__global__ __launch_bounds__(256) void zero_ctrl(int* __restrict__ ctrl) {
    const int tid = threadIdx.x;
#pragma unroll
    for (int i = 0; i < 3; ++i) ctrl[i * 256 + tid] = 0;  // hist, cursor, tilemask
}

// ------- Kernel 1 (fused): gating -> wbuf/tmask/hist + x->Xbf | build Bt ---
__global__ __launch_bounds__(256) void gating_cvt_bt(
    const float* __restrict__ x, const float* __restrict__ Wg,
    const float* __restrict__ bg, const float* __restrict__ Wt,
    const float* __restrict__ bt, float* __restrict__ wbuf,
    unsigned short* __restrict__ Xbf,
    const float* __restrict__ Wexp, unsigned short* __restrict__ Bt,
    int* __restrict__ tmask, int* __restrict__ hist)
{
    const int tid = threadIdx.x;

    if (blockIdx.x >= 512) {
        __shared__ float tile[64][65];
        const int bb = blockIdx.x - 512;
        const int k0 = (bb & 63) * 64;
        const int n0 = (bb >> 6) * 64;
        const int r = tid >> 4, cq = tid & 15;
#pragma unroll
        for (int p = 0; p < 4; ++p) {
            const int rr = p * 16 + r;
            const float4 v = *(const float4*)(Wexp + (size_t)(k0 + rr) * 512 + n0 + cq * 4);
            tile[rr][cq * 4 + 0] = v.x;
            tile[rr][cq * 4 + 1] = v.y;
            tile[rr][cq * 4 + 2] = v.z;
            tile[rr][cq * 4 + 3] = v.w;
        }
        __syncthreads();
        const int rn = tid >> 2;
        const int kq = tid & 3;
        alignas(16) unsigned short buf[16];
#pragma unroll
        for (int j = 0; j < 16; ++j) buf[j] = f2bf(tile[kq * 16 + j][rn]);
        unsigned short* dst = Bt + (size_t)(n0 + rn) * KDIM + k0 + kq * 16;
        *(uint4*)(dst) = *(const uint4*)(buf);
        *(uint4*)(dst + 8) = *(const uint4*)(buf + 8);
        return;
    }

    __shared__ int shist[256];
    shist[tid] = 0;
    __syncthreads();

    const int wv = tid >> 6;
    const int lane = tid & 63;

    float4 wg[16];
    {
        const float4* wgp = (const float4*)(Wg + lane * 64);
#pragma unroll
        for (int c = 0; c < 16; ++c) wg[c] = wgp[c];
    }
    const float4 wt0 = *(const float4*)(Wt + lane * 8);
    const float4 wt1 = *(const float4*)(Wt + lane * 8 + 4);
    const float bgv[8] = {bg[0], bg[1], bg[2], bg[3], bg[4], bg[5], bg[6], bg[7]};
    const float btv = bt[0];

    for (int it = 0; it < 16; ++it) {
        const int t = blockIdx.x * 64 + wv * 16 + it;
        const float* xp = x + (size_t)t * 512 + lane * 8;
        const float4 a0 = *(const float4*)(xp);
        const float4 a1 = *(const float4*)(xp + 4);

        uint2 pk0, pk1;
        pk0.x = pk2(a0.x, a0.y);
        pk0.y = pk2(a0.z, a0.w);
        pk1.x = pk2(a1.x, a1.y);
        pk1.y = pk2(a1.z, a1.w);
        uint2* xd = (uint2*)(Xbf + (size_t)t * 512 + lane * 8);
        xd[0] = pk0;
        xd[1] = pk1;

        const float xv[8] = {a0.x, a0.y, a0.z, a0.w, a1.x, a1.y, a1.z, a1.w};
        const float wtv[8] = {wt0.x, wt0.y, wt0.z, wt0.w, wt1.x, wt1.y, wt1.z, wt1.w};
        float g[9];
#pragma unroll
        for (int e = 0; e < 9; ++e) g[e] = 0.f;
#pragma unroll
        for (int j = 0; j < 8; ++j) {
            const float4 wlo = wg[j * 2];
            const float4 whi = wg[j * 2 + 1];
            g[0] = fmaf(xv[j], wlo.x, g[0]);
            g[1] = fmaf(xv[j], wlo.y, g[1]);
            g[2] = fmaf(xv[j], wlo.z, g[2]);
            g[3] = fmaf(xv[j], wlo.w, g[3]);
            g[4] = fmaf(xv[j], whi.x, g[4]);
            g[5] = fmaf(xv[j], whi.y, g[5]);
            g[6] = fmaf(xv[j], whi.z, g[6]);
            g[7] = fmaf(xv[j], whi.w, g[7]);
            g[8] = fmaf(xv[j], wtv[j], g[8]);
        }
#pragma unroll
        for (int e = 0; e < 9; ++e) {
            g[e] += __shfl_xor(g[e], 1);
            g[e] += __shfl_xor(g[e], 2);
            g[e] += __shfl_xor(g[e], 4);
            g[e] += __shfl_xor(g[e], 8);
            g[e] += __shfl_xor(g[e], 16);
            g[e] += __shfl_xor(g[e], 32);
        }
        if (lane == 0) {
#pragma unroll
            for (int e = 0; e < 8; ++e) g[e] += bgv[e];
            g[8] += btv;
            float m = g[0];
#pragma unroll
            for (int e = 1; e < 8; ++e) m = fmaxf(m, g[e]);
            float s = 0.f;
            float p[8];
#pragma unroll
            for (int e = 0; e < 8; ++e) { p[e] = __expf(g[e] - m); s += p[e]; }
            const float inv = 1.f / s;
            const float thr = 0.25f / (1.f + __expf(-g[8]));
            float w8[8];
            float ws = 0.f;
            int mk = 0;
#pragma unroll
            for (int e = 0; e < 8; ++e) {
                float a = p[e] * inv - thr;
                w8[e] = a > 0.f ? a : 0.f;
                if (w8[e] > 0.f) mk |= (1 << e);
                ws += w8[e];
            }
            if (ws == 0.f) ws = 1.f;
            const float invw = 1.f / ws;
            float4 o0, o1;
            o0.x = w8[0] * invw; o0.y = w8[1] * invw; o0.z = w8[2] * invw; o0.w = w8[3] * invw;
            o1.x = w8[4] * invw; o1.y = w8[5] * invw; o1.z = w8[6] * invw; o1.w = w8[7] * invw;
            float4* op = (float4*)(wbuf + (size_t)t * 8);
            op[0] = o0;
            op[1] = o1;
            tmask[t] = mk;
            atomicAdd(&shist[mk], 1);
        }
    }
    __syncthreads();
    const int v = shist[tid];
    if (v) atomicAdd(&hist[tid], v);
}

// ------------------ Kernel 2: exclusive scan of hist[256] ------------------
__global__ __launch_bounds__(256) void scan_offsets(
    const int* __restrict__ hist, int* __restrict__ offset)
{
    __shared__ int tmp[256];
    const int tid = threadIdx.x;
    const int v = hist[tid];
    tmp[tid] = v;
    __syncthreads();
    int acc = tmp[tid];
    for (int d = 1; d < 256; d <<= 1) {
        int t = (tid >= d) ? tmp[tid - d] : 0;
        __syncthreads();
        acc += t;
        tmp[tid] = acc;
        __syncthreads();
    }
    offset[tid] = acc - v;   // exclusive
}

// ------------------ Kernel 3: scatter perm + tile masks --------------------
__global__ __launch_bounds__(256) void scatter_perm(
    const int* __restrict__ tmask, const int* __restrict__ offset,
    int* __restrict__ cursor, int* __restrict__ perm, int* __restrict__ tilemask)
{
    const int t = blockIdx.x * 256 + threadIdx.x;
    const int mk = tmask[t];
    const int pos = offset[mk] + atomicAdd(&cursor[mk], 1);
    perm[pos] = t;
    if (mk) atomicOr(&tilemask[pos >> 7], mk);
}

// ------------- Kernel 4: sparse fold-GEMM (R5 structure + perm) ------------
// LDS tiles XOR-swizzled: element (row,k) at row*64 + ((k/8 ^ (row&7))*8)+k%8.
// Both operands via global_load_lds, lane chunk perm cg=(lane&7)^(lane>>3).
__global__ __launch_bounds__(256, 2) void moe_gemm(
    const unsigned short* __restrict__ Xbf, const float* __restrict__ wbuf,
    const float* __restrict__ bexp, const unsigned short* __restrict__ Bt,
    const int* __restrict__ perm, const int* __restrict__ tilemask,
    float* __restrict__ out)
{
    __shared__ alignas(16) unsigned short As[2 * 8192];  // 32 KB
    __shared__ alignas(16) unsigned short Bs[2 * 8192];  // 32 KB
    __shared__ float sWbT[8 * 128];                      // 4 KB [e][row]
    __shared__ float sBb[8 * 128];                       // 4 KB [e][col]
    __shared__ int sPerm[128];                           // 0.5 KB

    const int tid = threadIdx.x;
    const int wave = tid >> 6;
    const int lane = tid & 63;
    const int wm = wave >> 1;
    const int wn = wave & 1;
    const int lm = lane & 15;
    const int lq = lane >> 4;
    const int brow = lane >> 3;
    const int cg = (lane & 7) ^ brow;

    // t-tile interleaved across XCDs (stride 8 over sorted tiles -> balance);
    // 4 n-blocks of a t-tile are same-XCD consecutive (L2 sharing, R5-proven).
    const int lin = blockIdx.x;
    const int g = lin & 7;
    const int j_ = lin >> 3;              // 0..127
    const int tt = (j_ >> 2) * 8 + g;     // 0..255
    const int t0 = tt * 128;
    const int n0 = (j_ & 3) * 128;

    if (tid < 128) sPerm[tid] = perm[t0 + tid];
    __syncthreads();

    // gather sWbT[e][row] = wbuf[sPerm[row]][e]; load bias slice
    {
        const int row = tid >> 1, half = tid & 1;
        const int tok = sPerm[row];
        const float4 wv4 = *(const float4*)(wbuf + (size_t)tok * 8 + half * 4);
        sWbT[(half * 4 + 0) * 128 + row] = wv4.x;
        sWbT[(half * 4 + 1) * 128 + row] = wv4.y;
        sWbT[(half * 4 + 2) * 128 + row] = wv4.z;
        sWbT[(half * 4 + 3) * 128 + row] = wv4.w;
    }
    ((float4*)sBb)[tid] = *(const float4*)(bexp + (size_t)(tid >> 5) * 512 + n0 + (tid & 31) * 4);

    int tokA[4];
#pragma unroll
    for (int i = 0; i < 4; ++i) tokA[i] = sPerm[wave * 32 + i * 8 + brow];

    const int tm = tilemask[tt];

#define STAGE_A(d0_, buf_)                                                      \
    {                                                                           \
        _Pragma("unroll")                                                       \
        for (int i = 0; i < 4; ++i)                                             \
            async_copy16(Xbf + (size_t)tokA[i] * 512 + (d0_) + cg * 8,          \
                         As + (buf_) * 8192 + (wave * 32 + i * 8) * 64);        \
    }
#define STAGE_B(k0_, buf_)                                                      \
    {                                                                           \
        _Pragma("unroll")                                                       \
        for (int i = 0; i < 4; ++i)                                             \
            async_copy16(Bt + (size_t)(n0 + wave * 32 + i * 8 + brow) * KDIM + (k0_) + cg * 8, \
                         Bs + (buf_) * 8192 + (wave * 32 + i * 8) * 64);        \
    }

    floatx4 acc[4][4];
#pragma unroll
    for (int i = 0; i < 4; ++i)
#pragma unroll
        for (int j = 0; j < 4; ++j) acc[i][j] = (floatx4){0.f, 0.f, 0.f, 0.f};

    if (tm) {
        floatx4 tmp[4][4];
        int m = tm;
        int ec = __ffs(m) - 1;
        const int ne = __popc(m);

        // prologue: stage (ec, ks=0) into buffer 0
        STAGE_A(0, 0);
        STAGE_B(ec * 512, 0);
        __syncthreads();   // drains staging; sWbT/sBb/sPerm visible

        // tmp init: bias of ec
#pragma unroll
        for (int j = 0; j < 4; ++j) {
            const float bb = sBb[ec * 128 + wn * 64 + j * 16 + lm];
#pragma unroll
            for (int i = 0; i < 4; ++i) tmp[i][j] = (floatx4){bb, bb, bb, bb};
        }

        for (int ei = 0; ei < ne; ++ei) {
            const int m2 = m & (m - 1);
            const int en = m2 ? (__ffs(m2) - 1) : 0;
#pragma unroll
            for (int ks = 0; ks < 8; ++ks) {
                const int nb = ks & 1;  // global step parity (8 | ei*8)
                const bool last = (ei == ne - 1) && (ks == 7);
                if (!last) {
                    const int ep = (ks < 7) ? ec : en;
                    const int d0n = ((ks + 1) & 7) << 6;
                    STAGE_A(d0n, nb ^ 1);
                    STAGE_B(ep * 512 + d0n, nb ^ 1);
                }
                // compute step (ec, ks) from buffer nb
                const unsigned short* Ab = As + nb * 8192;
                const unsigned short* Bb = Bs + nb * 8192;
#pragma unroll
                for (int kk = 0; kk < 2; ++kk) {
                    const int ch = kk * 4 + lq;
                    short8 a[4], b[4];
#pragma unroll
                    for (int i = 0; i < 4; ++i) {
                        const int row = wm * 64 + i * 16 + lm;
                        a[i] = *(const short8*)(Ab + row * 64 + ((ch ^ (row & 7)) << 3));
                    }
#pragma unroll
                    for (int j = 0; j < 4; ++j) {
                        const int row = wn * 64 + j * 16 + lm;
                        b[j] = *(const short8*)(Bb + row * 64 + ((ch ^ (row & 7)) << 3));
                    }
#pragma unroll
                    for (int i = 0; i < 4; ++i)
#pragma unroll
                        for (int j = 0; j < 4; ++j)
                            tmp[i][j] = __builtin_amdgcn_mfma_f32_16x16x32_bf16(
                                a[i], b[j], tmp[i][j], 0, 0, 0);
                }
                if (ks == 7) {
                    // fold acc += w[:,ec] * tmp; reinit tmp with bias of en
#pragma unroll
                    for (int i = 0; i < 4; ++i) {
                        const float4 wq = *(const float4*)(sWbT + ec * 128 + wm * 64 + i * 16 + lq * 4);
#pragma unroll
                        for (int j = 0; j < 4; ++j) {
                            acc[i][j][0] = fmaf(wq.x, tmp[i][j][0], acc[i][j][0]);
                            acc[i][j][1] = fmaf(wq.y, tmp[i][j][1], acc[i][j][1]);
                            acc[i][j][2] = fmaf(wq.z, tmp[i][j][2], acc[i][j][2]);
                            acc[i][j][3] = fmaf(wq.w, tmp[i][j][3], acc[i][j][3]);
                        }
                    }
                    if (ei < ne - 1) {
#pragma unroll
                        for (int j = 0; j < 4; ++j) {
                            const float bb = sBb[en * 128 + wn * 64 + j * 16 + lm];
#pragma unroll
                            for (int i = 0; i < 4; ++i) tmp[i][j] = (floatx4){bb, bb, bb, bb};
                        }
                    }
                }
                __syncthreads();
            }
            m = m2;
            ec = en;
        }
    }

    // epilogue: scatter rows to out[perm[...]]; bias already folded in tmp
#pragma unroll
    for (int i = 0; i < 4; ++i)
#pragma unroll
        for (int r = 0; r < 4; ++r) {
            const int rowl = wm * 64 + i * 16 + lq * 4 + r;
            const int tok = sPerm[rowl];
            float* op = out + (size_t)tok * 512 + n0 + wn * 64 + lm;
#pragma unroll
            for (int j = 0; j < 4; ++j) op[j * 16] = acc[i][j][r];
        }
#undef STAGE_A
#undef STAGE_B
}

extern "C" void kernel_launch(void* const* d_in, const int* in_sizes, int n_in,
                              void* d_out, int out_size, void* d_ws, size_t ws_size,
                              hipStream_t stream) {
    const float* x   = (const float*)d_in[0];
    const float* Wg  = (const float*)d_in[1];
    const float* bg  = (const float*)d_in[2];
    const float* Wt  = (const float*)d_in[3];
    const float* bt  = (const float*)d_in[4];
    const float* Wex = (const float*)d_in[5];
    const float* bex = (const float*)d_in[6];
    float* out = (float*)d_out;

    // ws layout: Xbf 32MB | Bt 4MB | wbuf 1MB | tmask 128KB | perm 128KB |
    //            ctrl: hist[256] cursor[256] tilemask[256] offset[256]
    char* p = (char*)d_ws;
    unsigned short* Xbf = (unsigned short*)p;           p += (size_t)T_TOKENS * DDIM * 2;
    unsigned short* Bt  = (unsigned short*)p;           p += (size_t)DDIM * KDIM * 2;
    float* wbuf = (float*)p;                            p += (size_t)T_TOKENS * 8 * 4;
    int* tmask = (int*)p;                               p += (size_t)T_TOKENS * 4;
    int* perm = (int*)p;                                p += (size_t)T_TOKENS * 4;
    int* ctrl = (int*)p;   // [hist | cursor | tilemask | offset]
    int* hist = ctrl;
    int* cursor = ctrl + 256;
    int* tilemask = ctrl + 512;
    int* offset = ctrl + 768;

    zero_ctrl<<<1, 256, 0, stream>>>(ctrl);
    gating_cvt_bt<<<1024, 256, 0, stream>>>(x, Wg, bg, Wt, bt, wbuf, Xbf, Wex, Bt,
                                            tmask, hist);
    scan_offsets<<<1, 256, 0, stream>>>(hist, offset);
    scatter_perm<<<T_TOKENS / 256, 256, 0, stream>>>(tmask, offset, cursor, perm, tilemask);
    moe_gemm<<<1024, 256, 0, stream>>>(Xbf, wbuf, bex, Bt, perm, tilemask, out);
}